// Round 1
// baseline (410.432 us; speedup 1.0000x reference)
//
#include <hip/hip_runtime.h>
#include <math.h>

typedef unsigned short u16;
typedef unsigned int u32;
typedef __bf16 bf16x8 __attribute__((ext_vector_type(8)));
typedef float f32x4 __attribute__((ext_vector_type(4)));

__device__ __forceinline__ float bf2f(u16 v){ union{u32 u;float f;}c; c.u=((u32)v)<<16; return c.f; }
// compiler-cast bf16 (emits v_cvt_pk_bf16_f32 for pairs; RNE, same as old bit-trick)
__device__ __forceinline__ u16 f2bf(float f){ union{__bf16 h; u16 u;}c; c.h=(__bf16)f; return c.u; }
__device__ __forceinline__ u32 pk2(float a, float b){
  union{ __bf16 h[2]; u32 u; }c; c.h[0]=(__bf16)a; c.h[1]=(__bf16)b; return c.u;
}
// load 8 consecutive f32 (32B-aligned) -> 8 bf16 packed in uint4
__device__ __forceinline__ uint4 ld8f(const float* p){
  float4 x = ((const float4*)p)[0];
  float4 y = ((const float4*)p)[1];
  uint4 r; r.x=pk2(x.x,x.y); r.y=pk2(x.z,x.w); r.z=pk2(y.x,y.y); r.w=pk2(y.z,y.w);
  return r;
}
__device__ __forceinline__ float fsilu(float x){ return x/(1.f+__expf(-x)); }

// ---------------- setup kernels ----------------

__global__ void k_setup_edges(const int* __restrict__ e1_to_e2,
                              const float* __restrict__ rbf_e1,
                              const float* __restrict__ sph_e1,
                              u16* __restrict__ rbf1p,
                              float* __restrict__ sph_c, int E1) {
  int e = blockIdx.x*256 + threadIdx.x;
  if (e >= E1) return;
  int f = e1_to_e2[e];
  sph_c[f] = sph_e1[e*3+1];
  const float* s = rbf_e1 + (size_t)e*32;
  uint4* d = (uint4*)(rbf1p + (size_t)f*32);
  d[0]=ld8f(s); d[1]=ld8f(s+8); d[2]=ld8f(s+16); d[3]=ld8f(s+24);
}

__global__ void k_out_ptr(const int* __restrict__ src2, int* __restrict__ out_ptr,
                          int Nn, int E2) {
  int n = blockIdx.x*256 + threadIdx.x;
  if (n > Nn) return;
  int lo=0, hi=E2;
  while (lo<hi){ int m=(lo+hi)>>1; if (src2[m]<n) lo=m+1; else hi=m; }
  out_ptr[n]=lo;
}

__global__ void k_wbigt(const float* __restrict__ w1, u16* __restrict__ WbigT) {
  int id = blockIdx.x*256+threadIdx.x;
  if (id >= 384*448) return;
  int n = id/448, k = id%448;
  int q = n>>7, nn = n&127;
  int row = -1;
  if (k<128) row = q*128+k;
  else if (k<256) { if (q==0) row = 384+(k-128); }
  else if (k<384) { if (q==0) row = 512+(k-256); else if (q==1) row = 640+(k-256); }
  else if (k<416) { if (q==0) row = 768+(k-384); else if (q==1) row = 800+(k-384); }
  else { if (q==2) row = 832+(k-416); }
  WbigT[id] = (row>=0) ? f2bf(w1[row*128+nn]) : (u16)0;
}

__global__ void k_smallw(const float* __restrict__ w2, const float* __restrict__ wgw,
                         const float* __restrict__ wgt, const float* __restrict__ b2,
                         u16* __restrict__ WcT, u16* __restrict__ WgtT,
                         float* __restrict__ bc2) {
  int id = blockIdx.x*256+threadIdx.x;
  if (id < 16384) {
    int n = id&127, k = id>>7;
    float s = 0.f;
    for (int r=0;r<128;r++) s += w2[k*128+r]*wgw[r*128+n];
    WcT[n*128+k] = f2bf(s);
    WgtT[n*128+k] = f2bf(wgt[k*128+n]);
  } else if (id < 16384+128) {
    int n = id-16384;
    float s = 0.f;
    for (int r=0;r<128;r++) s += b2[r]*wgw[r*128+n];
    bc2[n] = s;
  }
}

// ---------------- wedge enumeration ----------------
__global__ __launch_bounds__(256, 8)
void k_enum(const int* __restrict__ src2, const int* __restrict__ dst2,
            const int* __restrict__ out_ptr, const float* __restrict__ sph_c,
            int4* __restrict__ wrec, int* __restrict__ cnt, int E2) {
  int id = blockIdx.x*256 + threadIdx.x;
  if (id >= E2*8) return;
  int gw = id >> 3, d = id & 7;
  int i = src2[gw], j = dst2[gw];
  int f = out_ptr[i] + d;
  if (f >= out_ptr[i+1]) return;
  int k = dst2[f];
  int lo = out_ptr[k], hi = out_ptr[k+1], hi0 = hi;
  while (lo<hi) { int m=(lo+hi)>>1; if (dst2[m]<j) lo=m+1; else hi=m; }
  if (lo < hi0 && dst2[lo]==j) {
    float cf = sph_c[f]*sph_c[lo];
    int slot = atomicAdd(&cnt[gw], 1);
    int4 r; r.x=f; r.y=lo; r.z=__float_as_int(cf); r.w=0;
    wrec[(size_t)gw*8 + slot] = r;
  }
}

// ---------------- wedge accumulation ----------------
__global__ __launch_bounds__(256, 8)
void k_wedge2(const u16* __restrict__ Q1, const u16* __restrict__ Q2,
              const u16* __restrict__ P3, const int4* __restrict__ wrec,
              const int* __restrict__ cnt, const float* __restrict__ w1,
              u16* __restrict__ S, int E2) {
  int gw = (int)((blockIdx.x*256 + threadIdx.x) >> 6);
  int lane = threadIdx.x & 63;
  if (gw >= E2) return;
  u32 p3u = ((const u32*)(P3 + (size_t)gw*128))[lane];
  float p30 = bf2f((u16)(p3u&0xffff)), p31 = bf2f((u16)(p3u>>16));
  float2 wv = ((const float2*)(w1 + 864*128))[lane];
  const u32* q1b = (const u32*)Q1;
  const u32* q2b = (const u32*)Q2;
  const int4* wr = wrec + (size_t)gw*8;
  int c = cnt[gw];
  float a0=0.f, a1=0.f;
  int w = 0;
  for (; w+2<=c; w+=2) {
    int4 rA = wr[w], rB = wr[w+1];
    u32 xA = q1b[(size_t)rA.x*64 + lane];
    u32 yA = q2b[(size_t)rA.y*64 + lane];
    u32 xB = q1b[(size_t)rB.x*64 + lane];
    u32 yB = q2b[(size_t)rB.y*64 + lane];
    float cfA = __int_as_float(rA.z), cfB = __int_as_float(rB.z);
    float x0 = p30 + bf2f((u16)(xA&0xffff)) + bf2f((u16)(yA&0xffff)) + cfA*wv.x;
    float x1 = p31 + bf2f((u16)(xA>>16))    + bf2f((u16)(yA>>16))    + cfA*wv.y;
    float z0 = p30 + bf2f((u16)(xB&0xffff)) + bf2f((u16)(yB&0xffff)) + cfB*wv.x;
    float z1 = p31 + bf2f((u16)(xB>>16))    + bf2f((u16)(yB>>16))    + cfB*wv.y;
    a0 += fsilu(x0) + fsilu(z0);
    a1 += fsilu(x1) + fsilu(z1);
  }
  if (w < c) {
    int4 rA = wr[w];
    u32 xA = q1b[(size_t)rA.x*64 + lane];
    u32 yA = q2b[(size_t)rA.y*64 + lane];
    float cfA = __int_as_float(rA.z);
    float x0 = p30 + bf2f((u16)(xA&0xffff)) + bf2f((u16)(yA&0xffff)) + cfA*wv.x;
    float x1 = p31 + bf2f((u16)(xA>>16))    + bf2f((u16)(yA>>16))    + cfA*wv.y;
    a0 += fsilu(x0);
    a1 += fsilu(x1);
  }
  ((u32*)(S + (size_t)gw*128))[lane] = pk2(a0, a1);
}

// ---------------- GEMM args ----------------
struct GArgs {
  const float* t_f32; const float* h; const float* rbf_e2;
  const u16* rbf1p; const u16* Asrc;
  const int* src2; const int* dst2; const int* cnt;
  const u16* Bmat; const u16* Gin;
  const float* b1; const float* bgw; const float* bgt; const float* bc2;
  u16* out0; u16* out1; u16* out2;
  float* outf;
  int M;
};

// ---------------- fused big GEMM (MODE 0): 128x384 tile, K=448 ----------------
// 512 threads = 8 waves (2 M x 4 N); double-buffered LDS, 1 barrier per K-step,
// register prefetch of next K-chunk issued right after the barrier.
__device__ __forceinline__ uint4 loadA0(const GArgs& a, long fa, int sa, int da,
                                        int part, int ks) {
  const int kb = ks*32;
  if (ks<4)   return ld8f(a.t_f32 + fa*128 + kb + part*8);
  if (ks<8)   return ld8f(a.h + (long)sa*128 + (kb-128) + part*8);
  if (ks<12)  return ld8f(a.h + (long)da*128 + (kb-256) + part*8);
  if (ks==12) return *(const uint4*)(a.rbf1p + fa*32 + part*8);
  return ld8f(a.rbf_e2 + fa*32 + part*8);
}
__device__ __forceinline__ void loadB0(const GArgs& a, int tid, int ks, uint4* wb) {
  #pragma unroll
  for (int s=0;s<3;s++){
    int id = tid + s*512;
    wb[s] = *(const uint4*)(a.Bmat + (long)(id>>2)*448 + ks*32 + (id&3)*8);
  }
}

__global__ __launch_bounds__(512)
void k_gemm0(GArgs a) {
  __shared__ u16 As[2][128*40];
  __shared__ u16 Bs[2][384*40];
  const int tid = threadIdx.x;
  const int bm = blockIdx.x;
  const int lane = tid & 63, wave = tid >> 6;
  const int wm = wave >> 2, wn = wave & 3;     // 2 x 4 wave grid
  const int quad = lane >> 4, l16 = lane & 15;

  const int part = tid & 3;        // k-subchunk (8 elems)
  const int ra = tid >> 2;         // A-row handled by this thread (0..127)
  long fa = (long)bm*128 + ra;
  if (fa >= a.M) fa = a.M-1;
  const int sa = a.src2[fa], da = a.dst2[fa];

  uint4 va = loadA0(a, fa, sa, da, part, 0);
  uint4 wb[3]; loadB0(a, tid, 0, wb);

  f32x4 acc[4][6] = {};
  for (int ks=0; ks<14; ks++) {
    const int cur = ks & 1;
    *(uint4*)(As[cur] + ra*40 + part*8) = va;
    #pragma unroll
    for (int s=0;s<3;s++){
      int id = tid + s*512;
      *(uint4*)(Bs[cur] + (id>>2)*40 + (id&3)*8) = wb[s];
    }
    __syncthreads();
    // prefetch next K-chunk: latency hides under this step's ds_read+MFMA
    if (ks < 13) { va = loadA0(a, fa, sa, da, part, ks+1); loadB0(a, tid, ks+1, wb); }
    bf16x8 af[4], bfr[6];
    #pragma unroll
    for (int t=0;t<4;t++)
      af[t]  = *(const bf16x8*)(As[cur] + (wm*64 + t*16 + l16)*40 + quad*8);
    #pragma unroll
    for (int u=0;u<6;u++)
      bfr[u] = *(const bf16x8*)(Bs[cur] + (wn*96 + u*16 + l16)*40 + quad*8);
    #pragma unroll
    for (int tm=0;tm<4;tm++)
      #pragma unroll
      for (int tn=0;tn<6;tn++)
        acc[tm][tn] = __builtin_amdgcn_mfma_f32_16x16x32_bf16(af[tm], bfr[tn], acc[tm][tn], 0,0,0);
  }

  // epilogue (C/D: col=lane&15, row=quad*4+reg)
  #pragma unroll
  for (int tm=0;tm<4;tm++) {
    const int rloc = wm*64 + tm*16 + quad*4;
    #pragma unroll
    for (int r=0;r<4;r++) {
      long row = (long)bm*128 + rloc + r;
      if (row >= a.M) continue;
      #pragma unroll
      for (int tn=0;tn<6;tn++) {
        const int col = wn*96 + tn*16 + l16;
        const int bn = col >> 7, cn = col & 127;
        float v = acc[tm][tn][r];
        if (bn==2) v += a.b1[cn];
        u16* dst = (bn==0)? a.out0 : (bn==1)? a.out1 : a.out2;
        dst[row*128 + cn] = f2bf(v);
      }
    }
  }
}

// ---------------- small MFMA GEMMs (MODE 1/2), unchanged structure ----------------
template<int MODE>
__global__ __launch_bounds__(256, 2)
void k_gemm(GArgs a) {
  constexpr int KT = 128;
  constexpr int NK = KT/32;
  __shared__ u16 As[128*40];
  __shared__ u16 Bs[128*40];
  const int tid = threadIdx.x;
  const int bm = blockIdx.x, bn = blockIdx.y;
  const int lane = tid & 63, wave = tid >> 6;
  const int wm = wave >> 1, wn = wave & 1;
  const int quad = lane >> 4, l16 = lane & 15;

  const int part = tid & 3;
  const int ra = tid >> 2;
  const int rb = ra + 64;
  long fa = (long)bm*128 + ra;
  long fb = (long)bm*128 + rb;
  if (fa >= a.M) fa = a.M-1;
  if (fb >= a.M) fb = a.M-1;

  f32x4 acc[4][4] = {};
  for (int ks=0; ks<NK; ks++) {
    const int kb = ks*32;
    uint4 va, vb;
    if constexpr (MODE==1) {
      va = *(const uint4*)(a.Asrc + fa*128 + kb + part*8);
      vb = *(const uint4*)(a.Asrc + fb*128 + kb + part*8);
    } else {
      va = ld8f(a.t_f32 + fa*128 + kb + part*8);
      vb = ld8f(a.t_f32 + fb*128 + kb + part*8);
    }
    uint4 wa = *(const uint4*)(a.Bmat + (long)(bn*128 + ra)*KT + kb + part*8);
    uint4 wbv = *(const uint4*)(a.Bmat + (long)(bn*128 + rb)*KT + kb + part*8);
    __syncthreads();
    *(uint4*)(As + ra*40 + part*8) = va;
    *(uint4*)(As + rb*40 + part*8) = vb;
    *(uint4*)(Bs + ra*40 + part*8) = wa;
    *(uint4*)(Bs + rb*40 + part*8) = wbv;
    __syncthreads();
    bf16x8 af[4], bfr[4];
    #pragma unroll
    for (int t=0;t<4;t++) {
      af[t]  = *(const bf16x8*)(As + (wm*64 + t*16 + l16)*40 + quad*8);
      bfr[t] = *(const bf16x8*)(Bs + (wn*64 + t*16 + l16)*40 + quad*8);
    }
    #pragma unroll
    for (int tm=0;tm<4;tm++)
      #pragma unroll
      for (int tn=0;tn<4;tn++)
        acc[tm][tn] = __builtin_amdgcn_mfma_f32_16x16x32_bf16(af[tm], bfr[tn], acc[tm][tn], 0,0,0);
  }

  #pragma unroll
  for (int tm=0;tm<4;tm++) {
    const int rloc = wm*64 + tm*16 + quad*4;
    #pragma unroll
    for (int r=0;r<4;r++) {
      long row = (long)bm*128 + rloc + r;
      if (row >= a.M) continue;
      #pragma unroll
      for (int tn=0;tn<4;tn++) {
        const int col = wn*64 + tn*16 + l16;
        float v = acc[tm][tn][r];
        if constexpr (MODE==1) {
          float u = v + (float)a.cnt[row]*a.bc2[col] + a.bgw[col];
          float g = 1.f/(1.f+__expf(-u));
          a.out0[row*128+col] = f2bf(g);
        } else {
          float vv = v + a.bgt[col];
          float th = 1.f - 2.f/(__expf(2.f*vv)+1.f);
          float t  = a.t_f32[row*128+col];
          float g  = bf2f(a.Gin[row*128+col]);
          a.outf[row*128+col] = t + g*th;
        }
      }
    }
  }
}

// ---------------- launch ----------------
extern "C" void kernel_launch(void* const* d_in, const int* in_sizes, int n_in,
                              void* d_out, int out_size, void* d_ws, size_t ws_size,
                              hipStream_t stream) {
  const float* t_e2  = (const float*)d_in[0];
  const float* h     = (const float*)d_in[1];
  const int* ei2     = (const int*)d_in[3];
  const int* e1_to_e2 = (const int*)d_in[4];
  const float* rbf_e1 = (const float*)d_in[7];
  const float* rbf_e2 = (const float*)d_in[8];
  const float* sph_e1 = (const float*)d_in[9];
  const float* w1  = (const float*)d_in[11];
  const float* b1  = (const float*)d_in[12];
  const float* w2  = (const float*)d_in[13];
  const float* b2  = (const float*)d_in[14];
  const float* wgw = (const float*)d_in[15];
  const float* bgw = (const float*)d_in[16];
  const float* wgt = (const float*)d_in[17];
  const float* bgt = (const float*)d_in[18];

  const int E2 = in_sizes[0]/128;
  const int Nn = in_sizes[1]/128;
  const int E1 = in_sizes[5];
  const int* src2 = ei2;
  const int* dst2 = ei2 + E2;

  // workspace carve (16B-aligned regions)
  char* p = (char*)d_ws;
  u16* Q1 = (u16*)p;       p += (size_t)E2*128*2;
  u16* Q2 = (u16*)p;       p += (size_t)E2*128*2;
  u16* P3 = (u16*)p;       p += (size_t)E2*128*2;   // aliased as S after wedge
  u16* rbf1p = (u16*)p;    p += (size_t)E2*32*2;
  u16* WbigT = (u16*)p;    p += (size_t)384*448*2;
  u16* WcT   = (u16*)p;    p += (size_t)128*128*2;
  u16* WgtT  = (u16*)p;    p += (size_t)128*128*2;
  float* sph_c = (float*)p; p += (size_t)E2*4;
  float* bc2   = (float*)p; p += 512;
  int* out_ptr = (int*)p;   p += (((size_t)(Nn+1)*4 + 63)/64)*64;
  int* cnt     = (int*)p;   p += (size_t)E2*4;
  int4* wrec   = (int4*)p;  p += (size_t)E2*8*16;
  u16* S = P3;   // alias: safe (row-local read-then-write in k_wedge2)
  u16* G = Q1;   // alias: Q1 dead after wedge stage

  hipMemsetAsync(cnt, 0, (size_t)E2*4, stream);

  k_setup_edges<<<(E1+255)/256, 256, 0, stream>>>(e1_to_e2, rbf_e1, sph_e1, rbf1p, sph_c, E1);
  k_out_ptr<<<(Nn+1+255)/256, 256, 0, stream>>>(src2, out_ptr, Nn, E2);
  k_wbigt<<<(384*448+255)/256, 256, 0, stream>>>(w1, WbigT);
  k_smallw<<<(16512+255)/256, 256, 0, stream>>>(w2, wgw, wgt, b2, WcT, WgtT, bc2);
  k_enum<<<(E2*8+255)/256, 256, 0, stream>>>(src2, dst2, out_ptr, sph_c, wrec, cnt, E2);

  const int Mb = (E2+127)/128;
  {
    GArgs a = {};
    a.t_f32=t_e2; a.h=h; a.rbf1p=rbf1p; a.rbf_e2=rbf_e2;
    a.src2=src2; a.dst2=dst2; a.Bmat=WbigT; a.b1=b1;
    a.out0=Q1; a.out1=Q2; a.out2=P3; a.M=E2;
    k_gemm0<<<Mb, 512, 0, stream>>>(a);
  }
  k_wedge2<<<(E2+3)/4, 256, 0, stream>>>(Q1, Q2, P3, wrec, cnt, w1, S, E2);
  {
    GArgs a = {};
    a.Asrc=S; a.cnt=cnt; a.Bmat=WcT; a.bgw=bgw; a.bc2=bc2;
    a.out0=G; a.M=E2;
    k_gemm<1><<<dim3(Mb,1), 256, 0, stream>>>(a);
  }
  {
    GArgs a = {};
    a.t_f32=t_e2; a.Bmat=WgtT; a.bgt=bgt; a.Gin=G;
    a.outf=(float*)d_out; a.M=E2;
    k_gemm<2><<<dim3(Mb,1), 256, 0, stream>>>(a);
  }
}

// Round 2
// 329.501 us; speedup vs baseline: 1.2456x; 1.2456x over previous
//
#include <hip/hip_runtime.h>
#include <math.h>

typedef unsigned short u16;
typedef unsigned int u32;
typedef __bf16 bf16x8 __attribute__((ext_vector_type(8)));
typedef float f32x4 __attribute__((ext_vector_type(4)));

__device__ __forceinline__ float bf2f(u16 v){ union{u32 u;float f;}c; c.u=((u32)v)<<16; return c.f; }
__device__ __forceinline__ u16 f2bf(float f){ union{__bf16 h; u16 u;}c; c.h=(__bf16)f; return c.u; }
__device__ __forceinline__ u32 pk2(float a, float b){
  union{ __bf16 h[2]; u32 u; }c; c.h[0]=(__bf16)a; c.h[1]=(__bf16)b; return c.u;
}
// load 8 consecutive f32 (32B-aligned) -> 8 bf16 packed in uint4
__device__ __forceinline__ uint4 ld8f(const float* p){
  float4 x = ((const float4*)p)[0];
  float4 y = ((const float4*)p)[1];
  uint4 r; r.x=pk2(x.x,x.y); r.y=pk2(x.z,x.w); r.z=pk2(y.x,y.y); r.w=pk2(y.z,y.w);
  return r;
}
__device__ __forceinline__ float fsilu(float x){ return x/(1.f+__expf(-x)); }

// ---------------- fused setup kernel ----------------
// block ranges: [0,nb0) setup_edges | [nb0,nb1) out_ptr | [nb1,nb2) wbigt |
//               [nb2,nb3) smallw    | [nb3,..) cnt zero
__global__ void k_setup_all(const int* __restrict__ e1_to_e2,
                            const float* __restrict__ rbf_e1,
                            const float* __restrict__ sph_e1,
                            u16* __restrict__ rbf1p, float* __restrict__ sph_c, int E1,
                            const int* __restrict__ src2, int* __restrict__ out_ptr,
                            int Nn, int E2,
                            const float* __restrict__ w1, u16* __restrict__ WbigT,
                            const float* __restrict__ w2, const float* __restrict__ wgw,
                            const float* __restrict__ wgt, const float* __restrict__ b2,
                            u16* __restrict__ WcT, u16* __restrict__ WgtT,
                            float* __restrict__ bc2, int* __restrict__ cnt,
                            int nb0, int nb1, int nb2, int nb3) {
  const int b = blockIdx.x, t = threadIdx.x;
  if (b < nb0) {
    // scatter rbf_e1 (f32->bf16) and sph_e1[:,1] into e2 ordering
    int e = b*256 + t;
    if (e >= E1) return;
    int f = e1_to_e2[e];
    sph_c[f] = sph_e1[e*3+1];
    const float* s = rbf_e1 + (size_t)e*32;
    uint4* d = (uint4*)(rbf1p + (size_t)f*32);
    d[0]=ld8f(s); d[1]=ld8f(s+8); d[2]=ld8f(s+16); d[3]=ld8f(s+24);
  } else if (b < nb1) {
    // CSR row pointers over key-sorted e2
    int n = (b-nb0)*256 + t;
    if (n > Nn) return;
    int lo=0, hi=E2;
    while (lo<hi){ int m=(lo+hi)>>1; if (src2[m]<n) lo=m+1; else hi=m; }
    out_ptr[n]=lo;
  } else if (b < nb2) {
    // padded transposed big weight WbigT[n(384)][k(448)]
    int id = (b-nb1)*256 + t;
    if (id >= 384*448) return;
    int n = id/448, k = id%448;
    int q = n>>7, nn = n&127;
    int row = -1;
    if (k<128) row = q*128+k;
    else if (k<256) { if (q==0) row = 384+(k-128); }
    else if (k<384) { if (q==0) row = 512+(k-256); else if (q==1) row = 640+(k-256); }
    else if (k<416) { if (q==0) row = 768+(k-384); else if (q==1) row = 800+(k-384); }
    else { if (q==2) row = 832+(k-416); }
    WbigT[id] = (row>=0) ? f2bf(w1[row*128+nn]) : (u16)0;
  } else if (b < nb3) {
    // WcT = (w2 @ wgw)^T, WgtT = wgt^T, bc2 = b2 @ wgw
    int id = (b-nb2)*256 + t;
    if (id < 16384) {
      int n = id&127, k = id>>7;
      float s = 0.f;
      for (int r=0;r<128;r++) s += w2[k*128+r]*wgw[r*128+n];
      WcT[n*128+k] = f2bf(s);
      WgtT[n*128+k] = f2bf(wgt[k*128+n]);
    } else if (id < 16384+128) {
      int n = id-16384;
      float s = 0.f;
      for (int r=0;r<128;r++) s += b2[r]*wgw[r*128+n];
      bc2[n] = s;
    }
  } else {
    int i = (b-nb3)*256 + t;
    if (i < E2) cnt[i] = 0;
  }
}

// ---------------- wedge enumeration ----------------
__global__ __launch_bounds__(256, 8)
void k_enum(const int* __restrict__ src2, const int* __restrict__ dst2,
            const int* __restrict__ out_ptr, const float* __restrict__ sph_c,
            int4* __restrict__ wrec, int* __restrict__ cnt, int E2) {
  int id = blockIdx.x*256 + threadIdx.x;
  if (id >= E2*8) return;
  int gw = id >> 3, d = id & 7;
  int i = src2[gw], j = dst2[gw];
  int f = out_ptr[i] + d;
  if (f >= out_ptr[i+1]) return;
  int k = dst2[f];
  int lo = out_ptr[k], hi = out_ptr[k+1], hi0 = hi;
  while (lo<hi) { int m=(lo+hi)>>1; if (dst2[m]<j) lo=m+1; else hi=m; }
  if (lo < hi0 && dst2[lo]==j) {
    float cf = sph_c[f]*sph_c[lo];
    int slot = atomicAdd(&cnt[gw], 1);
    int4 r; r.x=f; r.y=lo; r.z=__float_as_int(cf); r.w=0;
    wrec[(size_t)gw*8 + slot] = r;
  }
}

// ---------------- wedge accumulation ----------------
__global__ __launch_bounds__(256, 8)
void k_wedge2(const u16* __restrict__ Q1, const u16* __restrict__ Q2,
              const u16* __restrict__ P3, const int4* __restrict__ wrec,
              const int* __restrict__ cnt, const float* __restrict__ w1,
              u16* __restrict__ S, int E2) {
  int gw = (int)((blockIdx.x*256 + threadIdx.x) >> 6);
  int lane = threadIdx.x & 63;
  if (gw >= E2) return;
  u32 p3u = ((const u32*)(P3 + (size_t)gw*128))[lane];
  float p30 = bf2f((u16)(p3u&0xffff)), p31 = bf2f((u16)(p3u>>16));
  float2 wv = ((const float2*)(w1 + 864*128))[lane];
  const u32* q1b = (const u32*)Q1;
  const u32* q2b = (const u32*)Q2;
  const int4* wr = wrec + (size_t)gw*8;
  int c = cnt[gw];
  float a0=0.f, a1=0.f;
  int w = 0;
  for (; w+2<=c; w+=2) {
    int4 rA = wr[w], rB = wr[w+1];
    u32 xA = q1b[(size_t)rA.x*64 + lane];
    u32 yA = q2b[(size_t)rA.y*64 + lane];
    u32 xB = q1b[(size_t)rB.x*64 + lane];
    u32 yB = q2b[(size_t)rB.y*64 + lane];
    float cfA = __int_as_float(rA.z), cfB = __int_as_float(rB.z);
    float x0 = p30 + bf2f((u16)(xA&0xffff)) + bf2f((u16)(yA&0xffff)) + cfA*wv.x;
    float x1 = p31 + bf2f((u16)(xA>>16))    + bf2f((u16)(yA>>16))    + cfA*wv.y;
    float z0 = p30 + bf2f((u16)(xB&0xffff)) + bf2f((u16)(yB&0xffff)) + cfB*wv.x;
    float z1 = p31 + bf2f((u16)(xB>>16))    + bf2f((u16)(yB>>16))    + cfB*wv.y;
    a0 += fsilu(x0) + fsilu(z0);
    a1 += fsilu(x1) + fsilu(z1);
  }
  if (w < c) {
    int4 rA = wr[w];
    u32 xA = q1b[(size_t)rA.x*64 + lane];
    u32 yA = q2b[(size_t)rA.y*64 + lane];
    float cfA = __int_as_float(rA.z);
    float x0 = p30 + bf2f((u16)(xA&0xffff)) + bf2f((u16)(yA&0xffff)) + cfA*wv.x;
    float x1 = p31 + bf2f((u16)(xA>>16))    + bf2f((u16)(yA>>16))    + cfA*wv.y;
    a0 += fsilu(x0);
    a1 += fsilu(x1);
  }
  ((u32*)(S + (size_t)gw*128))[lane] = pk2(a0, a1);
}

// ---------------- GEMM args ----------------
struct GArgs {
  const float* t_f32; const float* h; const float* rbf_e2;
  const u16* rbf1p; const u16* Asrc;
  const int* src2; const int* dst2; const int* cnt;
  const u16* Bmat; const u16* Bmat2;
  const float* b1; const float* bgw; const float* bgt; const float* bc2;
  u16* out0; u16* out1; u16* out2;
  float* outf;
  int M;
};

// ---------------- big GEMM (proven round-0 structure + XCD swizzle) ----------------
// 1-D grid of 3*Mb blocks. Bijective XCD remap (m204): the 3 bn-siblings of each
// bm become consecutive work ids inside one XCD's contiguous chunk -> A rows are
// fetched into that XCD's L2 once instead of 3x from HBM.
__global__ __launch_bounds__(256, 2)
void k_gemm0(GArgs a) {
  const int nwg = gridDim.x;
  const int id  = blockIdx.x;
  const int xcd = id & 7, idx = id >> 3;
  const int q = nwg >> 3, r = nwg & 7;
  const int w = (xcd < r ? xcd*(q+1) : r*(q+1) + (xcd-r)*q) + idx;
  const int bm = w/3, bn = w - bm*3;

  constexpr int KT = 448;
  constexpr int NK = KT/32;
  __shared__ u16 As[128*40];
  __shared__ u16 Bs[128*40];
  const int tid = threadIdx.x;
  const int lane = tid & 63, wave = tid >> 6;
  const int wm = wave >> 1, wn = wave & 1;
  const int quad = lane >> 4, l16 = lane & 15;

  const int part = tid & 3;        // k-subchunk (8 elems)
  const int ra = tid >> 2;
  const int rb = ra + 64;
  long fa = (long)bm*128 + ra;
  long fb = (long)bm*128 + rb;
  if (fa >= a.M) fa = a.M-1;
  if (fb >= a.M) fb = a.M-1;
  const int sa=a.src2[fa], da=a.dst2[fa], sb=a.src2[fb], db=a.dst2[fb];

  f32x4 acc[4][4] = {};
  for (int ks=0; ks<NK; ks++) {
    const int kb = ks*32;
    uint4 va, vb;
    if (ks<4)       { va = ld8f(a.t_f32 + fa*128 + kb + part*8);
                      vb = ld8f(a.t_f32 + fb*128 + kb + part*8); }
    else if (ks<8)  { va = ld8f(a.h + (long)sa*128 + (kb-128) + part*8);
                      vb = ld8f(a.h + (long)sb*128 + (kb-128) + part*8); }
    else if (ks<12) { va = ld8f(a.h + (long)da*128 + (kb-256) + part*8);
                      vb = ld8f(a.h + (long)db*128 + (kb-256) + part*8); }
    else if (ks==12){ va = *(const uint4*)(a.rbf1p + fa*32 + part*8);
                      vb = *(const uint4*)(a.rbf1p + fb*32 + part*8); }
    else            { va = ld8f(a.rbf_e2 + fa*32 + part*8);
                      vb = ld8f(a.rbf_e2 + fb*32 + part*8); }
    uint4 wa = *(const uint4*)(a.Bmat + (long)(bn*128 + ra)*KT + kb + part*8);
    uint4 wb = *(const uint4*)(a.Bmat + (long)(bn*128 + rb)*KT + kb + part*8);
    __syncthreads();
    *(uint4*)(As + ra*40 + part*8) = va;
    *(uint4*)(As + rb*40 + part*8) = vb;
    *(uint4*)(Bs + ra*40 + part*8) = wa;
    *(uint4*)(Bs + rb*40 + part*8) = wb;
    __syncthreads();
    bf16x8 af[4], bfr[4];
    #pragma unroll
    for (int t=0;t<4;t++) {
      af[t]  = *(const bf16x8*)(As + (wm*64 + t*16 + l16)*40 + quad*8);
      bfr[t] = *(const bf16x8*)(Bs + (wn*64 + t*16 + l16)*40 + quad*8);
    }
    #pragma unroll
    for (int tm=0;tm<4;tm++)
      #pragma unroll
      for (int tn=0;tn<4;tn++)
        acc[tm][tn] = __builtin_amdgcn_mfma_f32_16x16x32_bf16(af[tm], bfr[tn], acc[tm][tn], 0,0,0);
  }

  // epilogue (C/D: col=lane&15, row=quad*4+reg)
  #pragma unroll
  for (int tm=0;tm<4;tm++) {
    const int rloc = wm*64 + tm*16 + quad*4;
    #pragma unroll
    for (int r=0;r<4;r++) {
      long row = (long)bm*128 + rloc + r;
      if (row >= a.M) continue;
      #pragma unroll
      for (int tn=0;tn<4;tn++) {
        const int col = wn*64 + tn*16 + l16;
        float v = acc[tm][tn][r];
        u16* dst = (bn==0)? a.out0 : (bn==1)? a.out1 : a.out2;
        if (bn==2) v += a.b1[col];
        dst[row*128 + col] = f2bf(v);
      }
    }
  }
}

// ---------------- fused gate GEMMs (old MODE1 + MODE2) ----------------
// acc1 = S @ WcT, acc2 = bf16(t) @ WgtT, combined epilogue; G never hits memory.
__global__ __launch_bounds__(256, 2)
void k_gemm12(GArgs a) {
  __shared__ u16 As[128*40];
  __shared__ u16 Bs[128*40];
  const int tid = threadIdx.x;
  const int bm = blockIdx.x;
  const int lane = tid & 63, wave = tid >> 6;
  const int wm = wave >> 1, wn = wave & 1;
  const int quad = lane >> 4, l16 = lane & 15;

  const int part = tid & 3;
  const int ra = tid >> 2;
  const int rb = ra + 64;
  long fa = (long)bm*128 + ra;
  long fb = (long)bm*128 + rb;
  if (fa >= a.M) fa = a.M-1;
  if (fb >= a.M) fb = a.M-1;

  f32x4 acc1[4][4] = {};
  f32x4 acc2[4][4] = {};
  // pass 1: S @ WcT
  for (int ks=0; ks<4; ks++) {
    const int kb = ks*32;
    uint4 va = *(const uint4*)(a.Asrc + fa*128 + kb + part*8);
    uint4 vb = *(const uint4*)(a.Asrc + fb*128 + kb + part*8);
    uint4 wa = *(const uint4*)(a.Bmat + (long)ra*128 + kb + part*8);
    uint4 wbv= *(const uint4*)(a.Bmat + (long)rb*128 + kb + part*8);
    __syncthreads();
    *(uint4*)(As + ra*40 + part*8) = va;
    *(uint4*)(As + rb*40 + part*8) = vb;
    *(uint4*)(Bs + ra*40 + part*8) = wa;
    *(uint4*)(Bs + rb*40 + part*8) = wbv;
    __syncthreads();
    bf16x8 af[4], bfr[4];
    #pragma unroll
    for (int t=0;t<4;t++) {
      af[t]  = *(const bf16x8*)(As + (wm*64 + t*16 + l16)*40 + quad*8);
      bfr[t] = *(const bf16x8*)(Bs + (wn*64 + t*16 + l16)*40 + quad*8);
    }
    #pragma unroll
    for (int tm=0;tm<4;tm++)
      #pragma unroll
      for (int tn=0;tn<4;tn++)
        acc1[tm][tn] = __builtin_amdgcn_mfma_f32_16x16x32_bf16(af[tm], bfr[tn], acc1[tm][tn], 0,0,0);
  }
  // pass 2: bf16(t) @ WgtT
  for (int ks=0; ks<4; ks++) {
    const int kb = ks*32;
    uint4 va = ld8f(a.t_f32 + fa*128 + kb + part*8);
    uint4 vb = ld8f(a.t_f32 + fb*128 + kb + part*8);
    uint4 wa = *(const uint4*)(a.Bmat2 + (long)ra*128 + kb + part*8);
    uint4 wbv= *(const uint4*)(a.Bmat2 + (long)rb*128 + kb + part*8);
    __syncthreads();
    *(uint4*)(As + ra*40 + part*8) = va;
    *(uint4*)(As + rb*40 + part*8) = vb;
    *(uint4*)(Bs + ra*40 + part*8) = wa;
    *(uint4*)(Bs + rb*40 + part*8) = wbv;
    __syncthreads();
    bf16x8 af[4], bfr[4];
    #pragma unroll
    for (int t=0;t<4;t++) {
      af[t]  = *(const bf16x8*)(As + (wm*64 + t*16 + l16)*40 + quad*8);
      bfr[t] = *(const bf16x8*)(Bs + (wn*64 + t*16 + l16)*40 + quad*8);
    }
    #pragma unroll
    for (int tm=0;tm<4;tm++)
      #pragma unroll
      for (int tn=0;tn<4;tn++)
        acc2[tm][tn] = __builtin_amdgcn_mfma_f32_16x16x32_bf16(af[tm], bfr[tn], acc2[tm][tn], 0,0,0);
  }

  // combined epilogue
  #pragma unroll
  for (int tm=0;tm<4;tm++) {
    const int rloc = wm*64 + tm*16 + quad*4;
    #pragma unroll
    for (int r=0;r<4;r++) {
      long row = (long)bm*128 + rloc + r;
      if (row >= a.M) continue;
      #pragma unroll
      for (int tn=0;tn<4;tn++) {
        const int col = wn*64 + tn*16 + l16;
        float u = acc1[tm][tn][r] + (float)a.cnt[row]*a.bc2[col] + a.bgw[col];
        float g = 1.f/(1.f+__expf(-u));
        float vv = acc2[tm][tn][r] + a.bgt[col];
        float th = 1.f - 2.f/(__expf(2.f*vv)+1.f);
        float t  = a.t_f32[row*128+col];
        a.outf[row*128+col] = t + g*th;
      }
    }
  }
}

// ---------------- launch ----------------
extern "C" void kernel_launch(void* const* d_in, const int* in_sizes, int n_in,
                              void* d_out, int out_size, void* d_ws, size_t ws_size,
                              hipStream_t stream) {
  const float* t_e2  = (const float*)d_in[0];
  const float* h     = (const float*)d_in[1];
  const int* ei2     = (const int*)d_in[3];
  const int* e1_to_e2 = (const int*)d_in[4];
  const float* rbf_e1 = (const float*)d_in[7];
  const float* rbf_e2 = (const float*)d_in[8];
  const float* sph_e1 = (const float*)d_in[9];
  const float* w1  = (const float*)d_in[11];
  const float* b1  = (const float*)d_in[12];
  const float* w2  = (const float*)d_in[13];
  const float* b2  = (const float*)d_in[14];
  const float* wgw = (const float*)d_in[15];
  const float* bgw = (const float*)d_in[16];
  const float* wgt = (const float*)d_in[17];
  const float* bgt = (const float*)d_in[18];

  const int E2 = in_sizes[0]/128;
  const int Nn = in_sizes[1]/128;
  const int E1 = in_sizes[5];
  const int* src2 = ei2;
  const int* dst2 = ei2 + E2;

  // workspace carve (16B-aligned regions)
  char* p = (char*)d_ws;
  u16* Q1 = (u16*)p;       p += (size_t)E2*128*2;
  u16* Q2 = (u16*)p;       p += (size_t)E2*128*2;
  u16* P3 = (u16*)p;       p += (size_t)E2*128*2;   // aliased as S after wedge
  u16* rbf1p = (u16*)p;    p += (size_t)E2*32*2;
  u16* WbigT = (u16*)p;    p += (size_t)384*448*2;
  u16* WcT   = (u16*)p;    p += (size_t)128*128*2;
  u16* WgtT  = (u16*)p;    p += (size_t)128*128*2;
  float* sph_c = (float*)p; p += (size_t)E2*4;
  float* bc2   = (float*)p; p += 512;
  int* out_ptr = (int*)p;   p += (((size_t)(Nn+1)*4 + 63)/64)*64;
  int* cnt     = (int*)p;   p += (size_t)E2*4;
  int4* wrec   = (int4*)p;  p += (size_t)E2*8*16;
  u16* S = P3;   // alias: safe (row-local read-then-write in k_wedge2)

  // fused setup: block-range dispatch
  const int nb_edges = (E1+255)/256;
  const int nb_ptr   = (Nn+1+255)/256;
  const int nb_wbig  = (384*448+255)/256;
  const int nb_small = (16512+255)/256;
  const int nb_cnt   = (E2+255)/256;
  const int nb0 = nb_edges;
  const int nb1 = nb0 + nb_ptr;
  const int nb2 = nb1 + nb_wbig;
  const int nb3 = nb2 + nb_small;
  const int nbT = nb3 + nb_cnt;
  k_setup_all<<<nbT, 256, 0, stream>>>(e1_to_e2, rbf_e1, sph_e1, rbf1p, sph_c, E1,
                                       src2, out_ptr, Nn, E2,
                                       w1, WbigT, w2, wgw, wgt, b2,
                                       WcT, WgtT, bc2, cnt,
                                       nb0, nb1, nb2, nb3);
  k_enum<<<(E2*8+255)/256, 256, 0, stream>>>(src2, dst2, out_ptr, sph_c, wrec, cnt, E2);

  const int Mb = (E2+127)/128;
  {
    GArgs a = {};
    a.t_f32=t_e2; a.h=h; a.rbf1p=rbf1p; a.rbf_e2=rbf_e2;
    a.src2=src2; a.dst2=dst2; a.Bmat=WbigT; a.b1=b1;
    a.out0=Q1; a.out1=Q2; a.out2=P3; a.M=E2;
    k_gemm0<<<Mb*3, 256, 0, stream>>>(a);
  }
  k_wedge2<<<(E2+3)/4, 256, 0, stream>>>(Q1, Q2, P3, wrec, cnt, w1, S, E2);
  {
    GArgs a = {};
    a.Asrc=S; a.cnt=cnt; a.Bmat=WcT; a.Bmat2=WgtT;
    a.bgw=bgw; a.bgt=bgt; a.bc2=bc2; a.t_f32=t_e2;
    a.outf=(float*)d_out; a.M=E2;
    k_gemm12<<<Mb, 256, 0, stream>>>(a);
  }
}

// Round 3
// 295.004 us; speedup vs baseline: 1.3913x; 1.1169x over previous
//
#include <hip/hip_runtime.h>
#include <math.h>

typedef unsigned short u16;
typedef unsigned int u32;
typedef __bf16 bf16x8 __attribute__((ext_vector_type(8)));
typedef float f32x4 __attribute__((ext_vector_type(4)));

__device__ __forceinline__ float bf2f(u16 v){ union{u32 u;float f;}c; c.u=((u32)v)<<16; return c.f; }
__device__ __forceinline__ u16 f2bf(float f){ union{__bf16 h; u16 u;}c; c.h=(__bf16)f; return c.u; }
__device__ __forceinline__ u32 pk2(float a, float b){
  union{ __bf16 h[2]; u32 u; }c; c.h[0]=(__bf16)a; c.h[1]=(__bf16)b; return c.u;
}
// load 8 consecutive f32 (32B-aligned) -> 8 bf16 packed in uint4
__device__ __forceinline__ uint4 ld8f(const float* p){
  float4 x = ((const float4*)p)[0];
  float4 y = ((const float4*)p)[1];
  uint4 r; r.x=pk2(x.x,x.y); r.y=pk2(x.z,x.w); r.z=pk2(y.x,y.y); r.w=pk2(y.z,y.w);
  return r;
}
__device__ __forceinline__ float fsilu(float x){ return x/(1.f+__expf(-x)); }

// ---------------- fused setup kernel ----------------
// block ranges: [0,nb0) setup_edges | [nb0,nb1) out_ptr | [nb1,nb2) compact W0/W1/W2 |
//               [nb2,nb3) smallw
__global__ void k_setup_all(const int* __restrict__ e1_to_e2,
                            const float* __restrict__ rbf_e1,
                            const float* __restrict__ sph_e1,
                            u16* __restrict__ rbf1p, float* __restrict__ sph_c, int E1,
                            const int* __restrict__ src2, int* __restrict__ out_ptr,
                            int Nn, int E2,
                            const float* __restrict__ w1,
                            u16* __restrict__ W0T, u16* __restrict__ W1T,
                            u16* __restrict__ W2T,
                            const float* __restrict__ w2, const float* __restrict__ wgw,
                            const float* __restrict__ wgt, const float* __restrict__ b2,
                            u16* __restrict__ WcT, u16* __restrict__ WgtT,
                            float* __restrict__ bc2,
                            int nb0, int nb1, int nb2) {
  const int b = blockIdx.x, t = threadIdx.x;
  if (b < nb0) {
    // scatter rbf_e1 (f32->bf16) and sph_e1[:,1] into e2 ordering
    int e = b*256 + t;
    if (e >= E1) return;
    int f = e1_to_e2[e];
    sph_c[f] = sph_e1[e*3+1];
    const float* s = rbf_e1 + (size_t)e*32;
    uint4* d = (uint4*)(rbf1p + (size_t)f*32);
    d[0]=ld8f(s); d[1]=ld8f(s+8); d[2]=ld8f(s+16); d[3]=ld8f(s+24);
  } else if (b < nb1) {
    // CSR row pointers over key-sorted e2
    int n = (b-nb0)*256 + t;
    if (n > Nn) return;
    int lo=0, hi=E2;
    while (lo<hi){ int m=(lo+hi)>>1; if (src2[m]<n) lo=m+1; else hi=m; }
    out_ptr[n]=lo;
  } else if (b < nb2) {
    // compact transposed weights.
    // W0T[128][416]: k<128 -> w1 row k (t1) | 128-255 -> 384+(k-128) (h_i)
    //                | 256-383 -> 512+(k-256) (h_k) | 384-415 -> 768+(k-384) (rbf1 ik)
    // W1T[128][288]: k<128 -> 128+k (t2) | 128-255 -> 640+(k-128) (h_j)
    //                | 256-287 -> 800+(k-256) (rbf1 kj)
    // W2T[128][160]: k<128 -> 256+k (t3) | 128-159 -> 832+(k-128) (rbf2)
    int id = (b-nb1)*256 + t;
    if (id < 128*416) {
      int n = id/416, k = id - n*416;
      int row = (k<128)? k : (k<256)? 384+(k-128) : (k<384)? 512+(k-256) : 768+(k-384);
      W0T[id] = f2bf(w1[row*128+n]);
    } else if (id < 128*(416+288)) {
      int id2 = id - 128*416;
      int n = id2/288, k = id2 - n*288;
      int row = (k<128)? 128+k : (k<256)? 640+(k-128) : 800+(k-256);
      W1T[id2] = f2bf(w1[row*128+n]);
    } else if (id < 128*864) {
      int id2 = id - 128*704;
      int n = id2/160, k = id2 - n*160;
      int row = (k<128)? 256+k : 832+(k-128);
      W2T[id2] = f2bf(w1[row*128+n]);
    }
  } else {
    // WcT = (w2 @ wgw)^T, WgtT = wgt^T, bc2 = b2 @ wgw
    int id = (b-nb2)*256 + t;
    if (id < 16384) {
      int n = id&127, k = id>>7;
      float s = 0.f;
      for (int r=0;r<128;r++) s += w2[k*128+r]*wgw[r*128+n];
      WcT[n*128+k] = f2bf(s);
      WgtT[n*128+k] = f2bf(wgt[k*128+n]);
    } else if (id < 16384+128) {
      int n = id-16384;
      float s = 0.f;
      for (int r=0;r<128;r++) s += b2[r]*wgw[r*128+n];
      bc2[n] = s;
    }
  }
}

// ---------------- fused wedge enumeration + accumulation ----------------
// one wave per e2 edge. lanes 0..7 search the 8 out-edge candidates of src;
// ballot -> mask; wave iterates valid wedges (2-way paired for load ILP):
// S[gw] = sum_w silu(Q1[f_w] + Q2[lo_w] + P3[gw] + cf_w * w1[864]).
// S aliases P3 (row-local read-then-write). cnt[gw] = popcount(mask).
__global__ __launch_bounds__(256, 8)
void k_wedge(const int* __restrict__ src2, const int* __restrict__ dst2,
             const int* __restrict__ out_ptr, const float* __restrict__ sph_c,
             const u16* __restrict__ Q1, const u16* __restrict__ Q2,
             const u16* __restrict__ P3, const float* __restrict__ w1,
             u16* __restrict__ S, int* __restrict__ cnt, int E2) {
  int gw = (int)((blockIdx.x*256 + threadIdx.x) >> 6);
  int lane = threadIdx.x & 63;
  if (gw >= E2) return;
  int i = src2[gw], j = dst2[gw];
  int f = 0, lo = 0; float cf = 0.f; bool valid = false;
  if (lane < 8) {
    int ff = out_ptr[i] + lane;
    if (ff < out_ptr[i+1]) {
      int k = dst2[ff];
      int l = out_ptr[k], hh = out_ptr[k+1], h0 = hh;
      while (l<hh){ int m=(l+hh)>>1; if (dst2[m]<j) l=m+1; else hh=m; }
      if (l<h0 && dst2[l]==j){ valid=true; f=ff; lo=l; cf=sph_c[ff]*sph_c[l]; }
    }
  }
  unsigned long long mask = __ballot(valid);
  if (lane==0) cnt[gw] = __popcll(mask);
  u32 p3u = ((const u32*)(P3 + (size_t)gw*128))[lane];
  float p30 = bf2f((u16)(p3u&0xffff)), p31 = bf2f((u16)(p3u>>16));
  float2 wv = ((const float2*)(w1 + 864*128))[lane];
  const u32* q1b = (const u32*)Q1;
  const u32* q2b = (const u32*)Q2;
  float a0=0.f, a1=0.f;
  while (mask) {
    int bA = __ffsll(mask)-1; mask &= mask-1;
    int fA = __shfl(f,bA), lA = __shfl(lo,bA); float cA = __shfl(cf,bA);
    if (mask) {
      int bB = __ffsll(mask)-1; mask &= mask-1;
      int fB = __shfl(f,bB), lB = __shfl(lo,bB); float cB = __shfl(cf,bB);
      u32 xA = q1b[(size_t)fA*64+lane], yA = q2b[(size_t)lA*64+lane];
      u32 xB = q1b[(size_t)fB*64+lane], yB = q2b[(size_t)lB*64+lane];
      float x0 = p30 + bf2f((u16)(xA&0xffff)) + bf2f((u16)(yA&0xffff)) + cA*wv.x;
      float x1 = p31 + bf2f((u16)(xA>>16))    + bf2f((u16)(yA>>16))    + cA*wv.y;
      float z0 = p30 + bf2f((u16)(xB&0xffff)) + bf2f((u16)(yB&0xffff)) + cB*wv.x;
      float z1 = p31 + bf2f((u16)(xB>>16))    + bf2f((u16)(yB>>16))    + cB*wv.y;
      a0 += fsilu(x0) + fsilu(z0);
      a1 += fsilu(x1) + fsilu(z1);
    } else {
      u32 xA = q1b[(size_t)fA*64+lane], yA = q2b[(size_t)lA*64+lane];
      float x0 = p30 + bf2f((u16)(xA&0xffff)) + bf2f((u16)(yA&0xffff)) + cA*wv.x;
      float x1 = p31 + bf2f((u16)(xA>>16))    + bf2f((u16)(yA>>16))    + cA*wv.y;
      a0 += fsilu(x0);
      a1 += fsilu(x1);
    }
  }
  ((u32*)(S + (size_t)gw*128))[lane] = pk2(a0, a1);
}

// ---------------- GEMM args ----------------
struct GArgs {
  const float* t_f32; const float* h; const float* rbf_e2;
  const u16* rbf1p; const u16* Asrc;
  const int* src2; const int* dst2; const int* cnt;
  const u16* B0; const u16* B1; const u16* B2;
  const u16* Bmat; const u16* Bmat2;
  const float* b1; const float* bgw; const float* bgt; const float* bc2;
  u16* out0; u16* out1; u16* out2;
  float* outf;
  int M;
};

// ---------------- big GEMM: K-specialized per bn ----------------
// 1-D grid of 3*Mb blocks, bijective XCD remap so the 3 bn-siblings of each bm
// are consecutive within one XCD chunk (A rows hit that XCD's L2).
// bn=0: K=416 (t,h_i,h_k,rbf1)  bn=1: K=288 (t,h_j,rbf1)  bn=2: K=160 (t,rbf2)
__global__ __launch_bounds__(256, 2)
void k_gemm0(GArgs a) {
  const int nwg = gridDim.x;
  const int id  = blockIdx.x;
  const int xcd = id & 7, idx = id >> 3;
  const int q = nwg >> 3, r = nwg & 7;
  const int w = (xcd < r ? xcd*(q+1) : r*(q+1) + (xcd-r)*q) + idx;
  const int bm = w/3, bn = w - bm*3;

  __shared__ u16 As[128*40];
  __shared__ u16 Bs[128*40];
  const int tid = threadIdx.x;
  const int lane = tid & 63, wave = tid >> 6;
  const int wm = wave >> 1, wn = wave & 1;
  const int quad = lane >> 4, l16 = lane & 15;

  const int part = tid & 3;        // k-subchunk (8 elems)
  const int ra = tid >> 2;
  const int rb = ra + 64;
  long fa = (long)bm*128 + ra;
  long fb = (long)bm*128 + rb;
  if (fa >= a.M) fa = a.M-1;
  if (fb >= a.M) fb = a.M-1;
  int sa=0, sb=0, da=0, db=0;
  if (bn==0) { sa=a.src2[fa]; sb=a.src2[fb]; }
  if (bn<2)  { da=a.dst2[fa]; db=a.dst2[fb]; }

  const u16* Bp = (bn==0)? a.B0 : (bn==1)? a.B1 : a.B2;
  const int NK = (bn==0)? 13 : (bn==1)? 9 : 5;
  const int KT = NK*32;

  f32x4 acc[4][4] = {};
  for (int ks=0; ks<NK; ks++) {
    const int kb = ks*32;
    uint4 va, vb;
    if (ks<4)                    { va = ld8f(a.t_f32 + fa*128 + kb + part*8);
                                   vb = ld8f(a.t_f32 + fb*128 + kb + part*8); }
    else if (bn==0 && ks<8)      { va = ld8f(a.h + (long)sa*128 + (kb-128) + part*8);
                                   vb = ld8f(a.h + (long)sb*128 + (kb-128) + part*8); }
    else if (bn==0 && ks<12)     { va = ld8f(a.h + (long)da*128 + (kb-256) + part*8);
                                   vb = ld8f(a.h + (long)db*128 + (kb-256) + part*8); }
    else if (bn==1 && ks<8)      { va = ld8f(a.h + (long)da*128 + (kb-128) + part*8);
                                   vb = ld8f(a.h + (long)db*128 + (kb-128) + part*8); }
    else if (bn==2)              { va = ld8f(a.rbf_e2 + fa*32 + part*8);
                                   vb = ld8f(a.rbf_e2 + fb*32 + part*8); }
    else                         { va = *(const uint4*)(a.rbf1p + fa*32 + part*8);
                                   vb = *(const uint4*)(a.rbf1p + fb*32 + part*8); }
    uint4 wa = *(const uint4*)(Bp + (long)ra*KT + kb + part*8);
    uint4 wb = *(const uint4*)(Bp + (long)rb*KT + kb + part*8);
    __syncthreads();
    *(uint4*)(As + ra*40 + part*8) = va;
    *(uint4*)(As + rb*40 + part*8) = vb;
    *(uint4*)(Bs + ra*40 + part*8) = wa;
    *(uint4*)(Bs + rb*40 + part*8) = wb;
    __syncthreads();
    bf16x8 af[4], bfr[4];
    #pragma unroll
    for (int t=0;t<4;t++) {
      af[t]  = *(const bf16x8*)(As + (wm*64 + t*16 + l16)*40 + quad*8);
      bfr[t] = *(const bf16x8*)(Bs + (wn*64 + t*16 + l16)*40 + quad*8);
    }
    #pragma unroll
    for (int tm=0;tm<4;tm++)
      #pragma unroll
      for (int tn=0;tn<4;tn++)
        acc[tm][tn] = __builtin_amdgcn_mfma_f32_16x16x32_bf16(af[tm], bfr[tn], acc[tm][tn], 0,0,0);
  }

  // epilogue (C/D: col=lane&15, row=quad*4+reg)
  #pragma unroll
  for (int tm=0;tm<4;tm++) {
    const int rloc = wm*64 + tm*16 + quad*4;
    #pragma unroll
    for (int r=0;r<4;r++) {
      long row = (long)bm*128 + rloc + r;
      if (row >= a.M) continue;
      #pragma unroll
      for (int tn=0;tn<4;tn++) {
        const int col = wn*64 + tn*16 + l16;
        float v = acc[tm][tn][r];
        u16* dst = (bn==0)? a.out0 : (bn==1)? a.out1 : a.out2;
        if (bn==2) v += a.b1[col];
        dst[row*128 + col] = f2bf(v);
      }
    }
  }
}

// ---------------- fused gate GEMMs ----------------
// acc1 = S @ WcT, acc2 = bf16(t) @ WgtT, combined epilogue; G never hits memory.
__global__ __launch_bounds__(256, 2)
void k_gemm12(GArgs a) {
  __shared__ u16 As[128*40];
  __shared__ u16 Bs[128*40];
  const int tid = threadIdx.x;
  const int bm = blockIdx.x;
  const int lane = tid & 63, wave = tid >> 6;
  const int wm = wave >> 1, wn = wave & 1;
  const int quad = lane >> 4, l16 = lane & 15;

  const int part = tid & 3;
  const int ra = tid >> 2;
  const int rb = ra + 64;
  long fa = (long)bm*128 + ra;
  long fb = (long)bm*128 + rb;
  if (fa >= a.M) fa = a.M-1;
  if (fb >= a.M) fb = a.M-1;

  f32x4 acc1[4][4] = {};
  f32x4 acc2[4][4] = {};
  // pass 1: S @ WcT
  for (int ks=0; ks<4; ks++) {
    const int kb = ks*32;
    uint4 va = *(const uint4*)(a.Asrc + fa*128 + kb + part*8);
    uint4 vb = *(const uint4*)(a.Asrc + fb*128 + kb + part*8);
    uint4 wa = *(const uint4*)(a.Bmat + (long)ra*128 + kb + part*8);
    uint4 wbv= *(const uint4*)(a.Bmat + (long)rb*128 + kb + part*8);
    __syncthreads();
    *(uint4*)(As + ra*40 + part*8) = va;
    *(uint4*)(As + rb*40 + part*8) = vb;
    *(uint4*)(Bs + ra*40 + part*8) = wa;
    *(uint4*)(Bs + rb*40 + part*8) = wbv;
    __syncthreads();
    bf16x8 af[4], bfr[4];
    #pragma unroll
    for (int t=0;t<4;t++) {
      af[t]  = *(const bf16x8*)(As + (wm*64 + t*16 + l16)*40 + quad*8);
      bfr[t] = *(const bf16x8*)(Bs + (wn*64 + t*16 + l16)*40 + quad*8);
    }
    #pragma unroll
    for (int tm=0;tm<4;tm++)
      #pragma unroll
      for (int tn=0;tn<4;tn++)
        acc1[tm][tn] = __builtin_amdgcn_mfma_f32_16x16x32_bf16(af[tm], bfr[tn], acc1[tm][tn], 0,0,0);
  }
  // pass 2: bf16(t) @ WgtT
  for (int ks=0; ks<4; ks++) {
    const int kb = ks*32;
    uint4 va = ld8f(a.t_f32 + fa*128 + kb + part*8);
    uint4 vb = ld8f(a.t_f32 + fb*128 + kb + part*8);
    uint4 wa = *(const uint4*)(a.Bmat2 + (long)ra*128 + kb + part*8);
    uint4 wbv= *(const uint4*)(a.Bmat2 + (long)rb*128 + kb + part*8);
    __syncthreads();
    *(uint4*)(As + ra*40 + part*8) = va;
    *(uint4*)(As + rb*40 + part*8) = vb;
    *(uint4*)(Bs + ra*40 + part*8) = wa;
    *(uint4*)(Bs + rb*40 + part*8) = wbv;
    __syncthreads();
    bf16x8 af[4], bfr[4];
    #pragma unroll
    for (int t=0;t<4;t++) {
      af[t]  = *(const bf16x8*)(As + (wm*64 + t*16 + l16)*40 + quad*8);
      bfr[t] = *(const bf16x8*)(Bs + (wn*64 + t*16 + l16)*40 + quad*8);
    }
    #pragma unroll
    for (int tm=0;tm<4;tm++)
      #pragma unroll
      for (int tn=0;tn<4;tn++)
        acc2[tm][tn] = __builtin_amdgcn_mfma_f32_16x16x32_bf16(af[tm], bfr[tn], acc2[tm][tn], 0,0,0);
  }

  // combined epilogue
  #pragma unroll
  for (int tm=0;tm<4;tm++) {
    const int rloc = wm*64 + tm*16 + quad*4;
    #pragma unroll
    for (int r=0;r<4;r++) {
      long row = (long)bm*128 + rloc + r;
      if (row >= a.M) continue;
      #pragma unroll
      for (int tn=0;tn<4;tn++) {
        const int col = wn*64 + tn*16 + l16;
        float u = acc1[tm][tn][r] + (float)a.cnt[row]*a.bc2[col] + a.bgw[col];
        float g = 1.f/(1.f+__expf(-u));
        float vv = acc2[tm][tn][r] + a.bgt[col];
        float th = 1.f - 2.f/(__expf(2.f*vv)+1.f);
        float t  = a.t_f32[row*128+col];
        a.outf[row*128+col] = t + g*th;
      }
    }
  }
}

// ---------------- launch ----------------
extern "C" void kernel_launch(void* const* d_in, const int* in_sizes, int n_in,
                              void* d_out, int out_size, void* d_ws, size_t ws_size,
                              hipStream_t stream) {
  const float* t_e2  = (const float*)d_in[0];
  const float* h     = (const float*)d_in[1];
  const int* ei2     = (const int*)d_in[3];
  const int* e1_to_e2 = (const int*)d_in[4];
  const float* rbf_e1 = (const float*)d_in[7];
  const float* rbf_e2 = (const float*)d_in[8];
  const float* sph_e1 = (const float*)d_in[9];
  const float* w1  = (const float*)d_in[11];
  const float* b1  = (const float*)d_in[12];
  const float* w2  = (const float*)d_in[13];
  const float* b2  = (const float*)d_in[14];
  const float* wgw = (const float*)d_in[15];
  const float* bgw = (const float*)d_in[16];
  const float* wgt = (const float*)d_in[17];
  const float* bgt = (const float*)d_in[18];

  const int E2 = in_sizes[0]/128;
  const int Nn = in_sizes[1]/128;
  const int E1 = in_sizes[5];
  const int* src2 = ei2;
  const int* dst2 = ei2 + E2;

  // workspace carve (16B-aligned regions)
  char* p = (char*)d_ws;
  u16* Q1 = (u16*)p;       p += (size_t)E2*128*2;
  u16* Q2 = (u16*)p;       p += (size_t)E2*128*2;
  u16* P3 = (u16*)p;       p += (size_t)E2*128*2;   // aliased as S after wedge
  u16* rbf1p = (u16*)p;    p += (size_t)E2*32*2;
  u16* W0T = (u16*)p;      p += (size_t)128*416*2;
  u16* W1T = (u16*)p;      p += (size_t)128*288*2;
  u16* W2T = (u16*)p;      p += (size_t)128*160*2;
  u16* WcT   = (u16*)p;    p += (size_t)128*128*2;
  u16* WgtT  = (u16*)p;    p += (size_t)128*128*2;
  float* sph_c = (float*)p; p += (size_t)E2*4;
  float* bc2   = (float*)p; p += 512;
  int* out_ptr = (int*)p;   p += (((size_t)(Nn+1)*4 + 63)/64)*64;
  int* cnt     = (int*)p;   p += (size_t)E2*4;
  u16* S = P3;   // alias: safe (row-local read-then-write in k_wedge)

  // fused setup: block-range dispatch
  const int nb_edges = (E1+255)/256;
  const int nb_ptr   = (Nn+1+255)/256;
  const int nb_w     = (128*864+255)/256;
  const int nb_small = (16512+255)/256;
  const int nb0 = nb_edges;
  const int nb1 = nb0 + nb_ptr;
  const int nb2 = nb1 + nb_w;
  const int nbT = nb2 + nb_small;
  k_setup_all<<<nbT, 256, 0, stream>>>(e1_to_e2, rbf_e1, sph_e1, rbf1p, sph_c, E1,
                                       src2, out_ptr, Nn, E2,
                                       w1, W0T, W1T, W2T,
                                       w2, wgw, wgt, b2,
                                       WcT, WgtT, bc2,
                                       nb0, nb1, nb2);

  const int Mb = (E2+127)/128;
  {
    GArgs a = {};
    a.t_f32=t_e2; a.h=h; a.rbf1p=rbf1p; a.rbf_e2=rbf_e2;
    a.src2=src2; a.dst2=dst2;
    a.B0=W0T; a.B1=W1T; a.B2=W2T; a.b1=b1;
    a.out0=Q1; a.out1=Q2; a.out2=P3; a.M=E2;
    k_gemm0<<<Mb*3, 256, 0, stream>>>(a);
  }
  k_wedge<<<(E2+3)/4, 256, 0, stream>>>(src2, dst2, out_ptr, sph_c,
                                        Q1, Q2, P3, w1, S, cnt, E2);
  {
    GArgs a = {};
    a.Asrc=S; a.cnt=cnt; a.Bmat=WcT; a.Bmat2=WgtT;
    a.bgw=bgw; a.bgt=bgt; a.bc2=bc2; a.t_f32=t_e2;
    a.outf=(float*)d_out; a.M=E2;
    k_gemm12<<<Mb, 256, 0, stream>>>(a);
  }
}

// Round 4
// 281.119 us; speedup vs baseline: 1.4600x; 1.0494x over previous
//
#include <hip/hip_runtime.h>
#include <math.h>

typedef unsigned short u16;
typedef unsigned int u32;
typedef __bf16 bf16x8 __attribute__((ext_vector_type(8)));
typedef float f32x4 __attribute__((ext_vector_type(4)));

__device__ __forceinline__ float bf2f(u16 v){ union{u32 u;float f;}c; c.u=((u32)v)<<16; return c.f; }
__device__ __forceinline__ u16 f2bf(float f){ union{__bf16 h; u16 u;}c; c.h=(__bf16)f; return c.u; }
__device__ __forceinline__ u32 pk2(float a, float b){
  union{ __bf16 h[2]; u32 u; }c; c.h[0]=(__bf16)a; c.h[1]=(__bf16)b; return c.u;
}
// load 8 consecutive f32 (32B-aligned) -> 8 bf16 packed in uint4
__device__ __forceinline__ uint4 ld8f(const float* p){
  float4 x = ((const float4*)p)[0];
  float4 y = ((const float4*)p)[1];
  uint4 r; r.x=pk2(x.x,x.y); r.y=pk2(x.z,x.w); r.z=pk2(y.x,y.y); r.w=pk2(y.z,y.w);
  return r;
}
// silu via v_rcp_f32 (1-ulp) instead of IEEE divide (~10-instr sequence)
__device__ __forceinline__ float fsilu(float x){
  return x*__builtin_amdgcn_rcpf(1.f+__expf(-x));
}

// ---------------- fused setup kernel ----------------
// block ranges: [0,nb0) setup_edges | [nb0,nb1) out_ptr | [nb1,nb2) compact W0/W1/W2 |
//               [nb2,..) smallw
__global__ void k_setup_all(const int* __restrict__ e1_to_e2,
                            const float* __restrict__ rbf_e1,
                            const float* __restrict__ sph_e1,
                            u16* __restrict__ rbf1p, float* __restrict__ sph_c, int E1,
                            const int* __restrict__ src2, int* __restrict__ out_ptr,
                            int Nn, int E2,
                            const float* __restrict__ w1,
                            u16* __restrict__ W0T, u16* __restrict__ W1T,
                            u16* __restrict__ W2T,
                            const float* __restrict__ w2, const float* __restrict__ wgw,
                            const float* __restrict__ wgt, const float* __restrict__ b2,
                            u16* __restrict__ WcT, u16* __restrict__ WgtT,
                            float* __restrict__ bc2,
                            int nb0, int nb1, int nb2) {
  const int b = blockIdx.x, t = threadIdx.x;
  if (b < nb0) {
    int e = b*256 + t;
    if (e >= E1) return;
    int f = e1_to_e2[e];
    sph_c[f] = sph_e1[e*3+1];
    const float* s = rbf_e1 + (size_t)e*32;
    uint4* d = (uint4*)(rbf1p + (size_t)f*32);
    d[0]=ld8f(s); d[1]=ld8f(s+8); d[2]=ld8f(s+16); d[3]=ld8f(s+24);
  } else if (b < nb1) {
    int n = (b-nb0)*256 + t;
    if (n > Nn) return;
    int lo=0, hi=E2;
    while (lo<hi){ int m=(lo+hi)>>1; if (src2[m]<n) lo=m+1; else hi=m; }
    out_ptr[n]=lo;
  } else if (b < nb2) {
    // compact transposed weights (see round-3 comment for layouts)
    int id = (b-nb1)*256 + t;
    if (id < 128*416) {
      int n = id/416, k = id - n*416;
      int row = (k<128)? k : (k<256)? 384+(k-128) : (k<384)? 512+(k-256) : 768+(k-384);
      W0T[id] = f2bf(w1[row*128+n]);
    } else if (id < 128*(416+288)) {
      int id2 = id - 128*416;
      int n = id2/288, k = id2 - n*288;
      int row = (k<128)? 128+k : (k<256)? 640+(k-128) : 800+(k-256);
      W1T[id2] = f2bf(w1[row*128+n]);
    } else if (id < 128*864) {
      int id2 = id - 128*704;
      int n = id2/160, k = id2 - n*160;
      int row = (k<128)? 256+k : 832+(k-128);
      W2T[id2] = f2bf(w1[row*128+n]);
    }
  } else {
    int id = (b-nb2)*256 + t;
    if (id < 16384) {
      int n = id&127, k = id>>7;
      float s = 0.f;
      for (int r=0;r<128;r++) s += w2[k*128+r]*wgw[r*128+n];
      WcT[n*128+k] = f2bf(s);
      WgtT[n*128+k] = f2bf(wgt[k*128+n]);
    } else if (id < 16384+128) {
      int n = id-16384;
      float s = 0.f;
      for (int r=0;r<128;r++) s += b2[r]*wgw[r*128+n];
      bc2[n] = s;
    }
  }
}

// ---------------- fused wedge enumeration + accumulation ----------------
// one wave per e2 edge. lanes 0..7 search the 8 out-edge candidates of src;
// ballot -> uniform mask. Then an unrolled ISSUE phase (readlane broadcast +
// all gather loads in flight, statically-indexed register slots) followed by
// an unrolled COMPUTE phase: S[gw] = sum_w silu(Q1[f]+Q2[lo]+P3[gw]+cf*w1r).
// S aliases P3 (row-local read-then-write). cnt[gw] = popcount(mask).
__global__ __launch_bounds__(256, 8)
void k_wedge(const int* __restrict__ src2, const int* __restrict__ dst2,
             const int* __restrict__ out_ptr, const float* __restrict__ sph_c,
             const u16* __restrict__ Q1, const u16* __restrict__ Q2,
             const u16* __restrict__ P3, const float* __restrict__ w1,
             u16* __restrict__ S, int* __restrict__ cnt, int E2) {
  int gw = (int)((blockIdx.x*256 + threadIdx.x) >> 6);
  int lane = threadIdx.x & 63;
  if (gw >= E2) return;
  int i = src2[gw], j = dst2[gw];
  int f = 0, lo = 0; float cf = 0.f; bool valid = false;
  if (lane < 8) {
    int ff = out_ptr[i] + lane;
    if (ff < out_ptr[i+1]) {
      int k = dst2[ff];
      int l = out_ptr[k], hh = out_ptr[k+1], h0 = hh;
      while (l<hh){ int m=(l+hh)>>1; if (dst2[m]<j) l=m+1; else hh=m; }
      if (l<h0 && dst2[l]==j){ valid=true; f=ff; lo=l; cf=sph_c[ff]*sph_c[l]; }
    }
  }
  unsigned long long mask = __ballot(valid);
  const int nw = __popcll(mask);
  if (lane==0) cnt[gw] = nw;
  u32 p3u = ((const u32*)(P3 + (size_t)gw*128))[lane];
  float p30 = bf2f((u16)(p3u&0xffff)), p31 = bf2f((u16)(p3u>>16));
  float2 wv = ((const float2*)(w1 + 864*128))[lane];
  const u32* q1b = (const u32*)Q1;
  const u32* q2b = (const u32*)Q2;

  // ISSUE phase: broadcast candidates via readlane (no LDS), launch all loads
  u32 xa[8], ya[8]; float ca[8];
  unsigned long long m2 = mask;
  #pragma unroll
  for (int s=0; s<8; s++) {
    if (s < nw) {
      int b = __ffsll((long long)m2)-1; m2 &= m2-1;
      int fA = __builtin_amdgcn_readlane(f, b);
      int lA = __builtin_amdgcn_readlane(lo, b);
      ca[s] = __int_as_float(__builtin_amdgcn_readlane(__float_as_int(cf), b));
      xa[s] = q1b[((size_t)(u32)fA<<6) + lane];
      ya[s] = q2b[((size_t)(u32)lA<<6) + lane];
    }
  }

  // COMPUTE phase
  float a0=0.f, a1=0.f;
  #pragma unroll
  for (int s=0; s<8; s++) {
    if (s < nw) {
      float b0 = fmaf(ca[s], wv.x, p30);
      float b1 = fmaf(ca[s], wv.y, p31);
      float x0 = b0 + bf2f((u16)(xa[s]&0xffff)) + bf2f((u16)(ya[s]&0xffff));
      float x1 = b1 + bf2f((u16)(xa[s]>>16))    + bf2f((u16)(ya[s]>>16));
      a0 += fsilu(x0);
      a1 += fsilu(x1);
    }
  }
  ((u32*)(S + (size_t)gw*128))[lane] = pk2(a0, a1);
}

// ---------------- GEMM args ----------------
struct GArgs {
  const float* t_f32; const float* h; const float* rbf_e2;
  const u16* rbf1p; const u16* Asrc;
  const int* src2; const int* dst2; const int* cnt;
  const u16* B0; const u16* B1; const u16* B2;
  const u16* Bmat; const u16* Bmat2;
  const float* b1; const float* bgw; const float* bgt; const float* bc2;
  u16* out0; u16* out1; u16* out2;
  float* outf;
  int M;
};

// ---------------- big GEMM: K-specialized per bn ----------------
// 1-D grid of 3*Mb blocks, bijective XCD remap so the 3 bn-siblings of each bm
// are consecutive within one XCD chunk (A rows hit that XCD's L2).
// bn=0: K=416 (t,h_i,h_k,rbf1)  bn=1: K=288 (t,h_j,rbf1)  bn=2: K=160 (t,rbf2)
__global__ __launch_bounds__(256, 2)
void k_gemm0(GArgs a) {
  const int nwg = gridDim.x;
  const int id  = blockIdx.x;
  const int xcd = id & 7, idx = id >> 3;
  const int q = nwg >> 3, r = nwg & 7;
  const int w = (xcd < r ? xcd*(q+1) : r*(q+1) + (xcd-r)*q) + idx;
  const int bm = w/3, bn = w - bm*3;

  __shared__ u16 As[128*40];
  __shared__ u16 Bs[128*40];
  const int tid = threadIdx.x;
  const int lane = tid & 63, wave = tid >> 6;
  const int wm = wave >> 1, wn = wave & 1;
  const int quad = lane >> 4, l16 = lane & 15;

  const int part = tid & 3;        // k-subchunk (8 elems)
  const int ra = tid >> 2;
  const int rb = ra + 64;
  long fa = (long)bm*128 + ra;
  long fb = (long)bm*128 + rb;
  if (fa >= a.M) fa = a.M-1;
  if (fb >= a.M) fb = a.M-1;
  int sa=0, sb=0, da=0, db=0;
  if (bn==0) { sa=a.src2[fa]; sb=a.src2[fb]; }
  if (bn<2)  { da=a.dst2[fa]; db=a.dst2[fb]; }

  const u16* Bp = (bn==0)? a.B0 : (bn==1)? a.B1 : a.B2;
  const int NK = (bn==0)? 13 : (bn==1)? 9 : 5;
  const int KT = NK*32;

  f32x4 acc[4][4] = {};
  for (int ks=0; ks<NK; ks++) {
    const int kb = ks*32;
    uint4 va, vb;
    if (ks<4)                    { va = ld8f(a.t_f32 + fa*128 + kb + part*8);
                                   vb = ld8f(a.t_f32 + fb*128 + kb + part*8); }
    else if (bn==0 && ks<8)      { va = ld8f(a.h + (long)sa*128 + (kb-128) + part*8);
                                   vb = ld8f(a.h + (long)sb*128 + (kb-128) + part*8); }
    else if (bn==0 && ks<12)     { va = ld8f(a.h + (long)da*128 + (kb-256) + part*8);
                                   vb = ld8f(a.h + (long)db*128 + (kb-256) + part*8); }
    else if (bn==1 && ks<8)      { va = ld8f(a.h + (long)da*128 + (kb-128) + part*8);
                                   vb = ld8f(a.h + (long)db*128 + (kb-128) + part*8); }
    else if (bn==2)              { va = ld8f(a.rbf_e2 + fa*32 + part*8);
                                   vb = ld8f(a.rbf_e2 + fb*32 + part*8); }
    else                         { va = *(const uint4*)(a.rbf1p + fa*32 + part*8);
                                   vb = *(const uint4*)(a.rbf1p + fb*32 + part*8); }
    uint4 wa = *(const uint4*)(Bp + (long)ra*KT + kb + part*8);
    uint4 wb = *(const uint4*)(Bp + (long)rb*KT + kb + part*8);
    __syncthreads();
    *(uint4*)(As + ra*40 + part*8) = va;
    *(uint4*)(As + rb*40 + part*8) = vb;
    *(uint4*)(Bs + ra*40 + part*8) = wa;
    *(uint4*)(Bs + rb*40 + part*8) = wb;
    __syncthreads();
    bf16x8 af[4], bfr[4];
    #pragma unroll
    for (int t=0;t<4;t++) {
      af[t]  = *(const bf16x8*)(As + (wm*64 + t*16 + l16)*40 + quad*8);
      bfr[t] = *(const bf16x8*)(Bs + (wn*64 + t*16 + l16)*40 + quad*8);
    }
    #pragma unroll
    for (int tm=0;tm<4;tm++)
      #pragma unroll
      for (int tn=0;tn<4;tn++)
        acc[tm][tn] = __builtin_amdgcn_mfma_f32_16x16x32_bf16(af[tm], bfr[tn], acc[tm][tn], 0,0,0);
  }

  // epilogue (C/D: col=lane&15, row=quad*4+reg)
  #pragma unroll
  for (int tm=0;tm<4;tm++) {
    const int rloc = wm*64 + tm*16 + quad*4;
    #pragma unroll
    for (int r=0;r<4;r++) {
      long row = (long)bm*128 + rloc + r;
      if (row >= a.M) continue;
      #pragma unroll
      for (int tn=0;tn<4;tn++) {
        const int col = wn*64 + tn*16 + l16;
        float v = acc[tm][tn][r];
        u16* dst = (bn==0)? a.out0 : (bn==1)? a.out1 : a.out2;
        if (bn==2) v += a.b1[col];
        dst[row*128 + col] = f2bf(v);
      }
    }
  }
}

// ---------------- fused gate GEMMs ----------------
// acc1 = S @ WcT, acc2 = bf16(t) @ WgtT, combined epilogue; G never hits memory.
__global__ __launch_bounds__(256, 2)
void k_gemm12(GArgs a) {
  __shared__ u16 As[128*40];
  __shared__ u16 Bs[128*40];
  const int tid = threadIdx.x;
  const int bm = blockIdx.x;
  const int lane = tid & 63, wave = tid >> 6;
  const int wm = wave >> 1, wn = wave & 1;
  const int quad = lane >> 4, l16 = lane & 15;

  const int part = tid & 3;
  const int ra = tid >> 2;
  const int rb = ra + 64;
  long fa = (long)bm*128 + ra;
  long fb = (long)bm*128 + rb;
  if (fa >= a.M) fa = a.M-1;
  if (fb >= a.M) fb = a.M-1;

  f32x4 acc1[4][4] = {};
  f32x4 acc2[4][4] = {};
  // pass 1: S @ WcT
  for (int ks=0; ks<4; ks++) {
    const int kb = ks*32;
    uint4 va = *(const uint4*)(a.Asrc + fa*128 + kb + part*8);
    uint4 vb = *(const uint4*)(a.Asrc + fb*128 + kb + part*8);
    uint4 wa = *(const uint4*)(a.Bmat + (long)ra*128 + kb + part*8);
    uint4 wbv= *(const uint4*)(a.Bmat + (long)rb*128 + kb + part*8);
    __syncthreads();
    *(uint4*)(As + ra*40 + part*8) = va;
    *(uint4*)(As + rb*40 + part*8) = vb;
    *(uint4*)(Bs + ra*40 + part*8) = wa;
    *(uint4*)(Bs + rb*40 + part*8) = wbv;
    __syncthreads();
    bf16x8 af[4], bfr[4];
    #pragma unroll
    for (int t=0;t<4;t++) {
      af[t]  = *(const bf16x8*)(As + (wm*64 + t*16 + l16)*40 + quad*8);
      bfr[t] = *(const bf16x8*)(Bs + (wn*64 + t*16 + l16)*40 + quad*8);
    }
    #pragma unroll
    for (int tm=0;tm<4;tm++)
      #pragma unroll
      for (int tn=0;tn<4;tn++)
        acc1[tm][tn] = __builtin_amdgcn_mfma_f32_16x16x32_bf16(af[tm], bfr[tn], acc1[tm][tn], 0,0,0);
  }
  // pass 2: bf16(t) @ WgtT
  for (int ks=0; ks<4; ks++) {
    const int kb = ks*32;
    uint4 va = ld8f(a.t_f32 + fa*128 + kb + part*8);
    uint4 vb = ld8f(a.t_f32 + fb*128 + kb + part*8);
    uint4 wa = *(const uint4*)(a.Bmat2 + (long)ra*128 + kb + part*8);
    uint4 wbv= *(const uint4*)(a.Bmat2 + (long)rb*128 + kb + part*8);
    __syncthreads();
    *(uint4*)(As + ra*40 + part*8) = va;
    *(uint4*)(As + rb*40 + part*8) = vb;
    *(uint4*)(Bs + ra*40 + part*8) = wa;
    *(uint4*)(Bs + rb*40 + part*8) = wbv;
    __syncthreads();
    bf16x8 af[4], bfr[4];
    #pragma unroll
    for (int t=0;t<4;t++) {
      af[t]  = *(const bf16x8*)(As + (wm*64 + t*16 + l16)*40 + quad*8);
      bfr[t] = *(const bf16x8*)(Bs + (wn*64 + t*16 + l16)*40 + quad*8);
    }
    #pragma unroll
    for (int tm=0;tm<4;tm++)
      #pragma unroll
      for (int tn=0;tn<4;tn++)
        acc2[tm][tn] = __builtin_amdgcn_mfma_f32_16x16x32_bf16(af[tm], bfr[tn], acc2[tm][tn], 0,0,0);
  }

  // combined epilogue (rcp-based sigmoid/tanh; 1-ulp, within tolerance)
  #pragma unroll
  for (int tm=0;tm<4;tm++) {
    const int rloc = wm*64 + tm*16 + quad*4;
    #pragma unroll
    for (int r=0;r<4;r++) {
      long row = (long)bm*128 + rloc + r;
      if (row >= a.M) continue;
      #pragma unroll
      for (int tn=0;tn<4;tn++) {
        const int col = wn*64 + tn*16 + l16;
        float u = acc1[tm][tn][r] + (float)a.cnt[row]*a.bc2[col] + a.bgw[col];
        float g = __builtin_amdgcn_rcpf(1.f+__expf(-u));
        float vv = acc2[tm][tn][r] + a.bgt[col];
        float th = 1.f - 2.f*__builtin_amdgcn_rcpf(__expf(2.f*vv)+1.f);
        float t  = a.t_f32[row*128+col];
        a.outf[row*128+col] = t + g*th;
      }
    }
  }
}

// ---------------- launch ----------------
extern "C" void kernel_launch(void* const* d_in, const int* in_sizes, int n_in,
                              void* d_out, int out_size, void* d_ws, size_t ws_size,
                              hipStream_t stream) {
  const float* t_e2  = (const float*)d_in[0];
  const float* h     = (const float*)d_in[1];
  const int* ei2     = (const int*)d_in[3];
  const int* e1_to_e2 = (const int*)d_in[4];
  const float* rbf_e1 = (const float*)d_in[7];
  const float* rbf_e2 = (const float*)d_in[8];
  const float* sph_e1 = (const float*)d_in[9];
  const float* w1  = (const float*)d_in[11];
  const float* b1  = (const float*)d_in[12];
  const float* w2  = (const float*)d_in[13];
  const float* b2  = (const float*)d_in[14];
  const float* wgw = (const float*)d_in[15];
  const float* bgw = (const float*)d_in[16];
  const float* wgt = (const float*)d_in[17];
  const float* bgt = (const float*)d_in[18];

  const int E2 = in_sizes[0]/128;
  const int Nn = in_sizes[1]/128;
  const int E1 = in_sizes[5];
  const int* src2 = ei2;
  const int* dst2 = ei2 + E2;

  // workspace carve (16B-aligned regions)
  char* p = (char*)d_ws;
  u16* Q1 = (u16*)p;       p += (size_t)E2*128*2;
  u16* Q2 = (u16*)p;       p += (size_t)E2*128*2;
  u16* P3 = (u16*)p;       p += (size_t)E2*128*2;   // aliased as S after wedge
  u16* rbf1p = (u16*)p;    p += (size_t)E2*32*2;
  u16* W0T = (u16*)p;      p += (size_t)128*416*2;
  u16* W1T = (u16*)p;      p += (size_t)128*288*2;
  u16* W2T = (u16*)p;      p += (size_t)128*160*2;
  u16* WcT   = (u16*)p;    p += (size_t)128*128*2;
  u16* WgtT  = (u16*)p;    p += (size_t)128*128*2;
  float* sph_c = (float*)p; p += (size_t)E2*4;
  float* bc2   = (float*)p; p += 512;
  int* out_ptr = (int*)p;   p += (((size_t)(Nn+1)*4 + 63)/64)*64;
  int* cnt     = (int*)p;   p += (size_t)E2*4;
  u16* S = P3;   // alias: safe (row-local read-then-write in k_wedge)

  // fused setup: block-range dispatch
  const int nb_edges = (E1+255)/256;
  const int nb_ptr   = (Nn+1+255)/256;
  const int nb_w     = (128*864+255)/256;
  const int nb_small = (16512+255)/256;
  const int nb0 = nb_edges;
  const int nb1 = nb0 + nb_ptr;
  const int nb2 = nb1 + nb_w;
  const int nbT = nb2 + nb_small;
  k_setup_all<<<nbT, 256, 0, stream>>>(e1_to_e2, rbf_e1, sph_e1, rbf1p, sph_c, E1,
                                       src2, out_ptr, Nn, E2,
                                       w1, W0T, W1T, W2T,
                                       w2, wgw, wgt, b2,
                                       WcT, WgtT, bc2,
                                       nb0, nb1, nb2);

  const int Mb = (E2+127)/128;
  {
    GArgs a = {};
    a.t_f32=t_e2; a.h=h; a.rbf1p=rbf1p; a.rbf_e2=rbf_e2;
    a.src2=src2; a.dst2=dst2;
    a.B0=W0T; a.B1=W1T; a.B2=W2T; a.b1=b1;
    a.out0=Q1; a.out1=Q2; a.out2=P3; a.M=E2;
    k_gemm0<<<Mb*3, 256, 0, stream>>>(a);
  }
  k_wedge<<<(E2+3)/4, 256, 0, stream>>>(src2, dst2, out_ptr, sph_c,
                                        Q1, Q2, P3, w1, S, cnt, E2);
  {
    GArgs a = {};
    a.Asrc=S; a.cnt=cnt; a.Bmat=WcT; a.Bmat2=WgtT;
    a.bgw=bgw; a.bgt=bgt; a.bc2=bc2; a.t_f32=t_e2;
    a.outf=(float*)d_out; a.M=E2;
    k_gemm12<<<Mb, 256, 0, stream>>>(a);
  }
}